// Round 3
// baseline (204.400 us; speedup 1.0000x reference)
//
#include <hip/hip_runtime.h>
#include <math.h>

// SoftSkeletonize: out = relu(img - dilate3(erode3(img))), (2,1,192,256,256) f32.
// erode = min-pool 3x3x3 (pad +inf), dilate = max-pool 3x3x3 (pad -inf).
//
// v3 (from v2): (a) B-stage task mapping TRANSPOSED (r = t%34, j = t/34) so
// every 16-lane phase covers 16 consecutive rows at a fixed strip -> bank
// quads (3r+2j) mod 8 hit 2-way (free) instead of 3-4-way; same for ebuf
// writes and b32 halo reads. (b) A2 stage removed: each thread global-loads
// its OWN 8 center values (coalesced, no h/w bounds checks) and keeps them in
// registers for the output stage; 136 halo cells staged by lanes 0..135.
// (c) CD=12 -> 1024 blocks = 4/CU with __launch_bounds__(256,4).

#define D_ 192
#define H_ 256
#define W_ 256
#define NB 2
#define TH 32
#define TW 64
#define CD 12
#define NCHUNK (D_ / CD)      // 16

#define RAW_H (TH + 4)        // 36 rows  <-> gh = h0-2 .. h0+33
#define RAW_W (TW + 8)        // 72 cols  <-> gw = w0-4 .. w0+67
#define RAW_S 76              // padded stride (x4 aligned, +3 quad/row rotation)
#define EB_H  (TH + 2)        // 34 rows  <-> gh = h0-1 .. h0+32
#define EB_S  76

#define NBTASK (EB_H * 9)     // 306 8-wide strip tasks (9 strips x 34 rows)
#define NHALO  136            // raw cells not covered by own-loads

__device__ __forceinline__ float min3f(float a, float b, float c) {
    return fminf(fminf(a, b), c);
}
__device__ __forceinline__ float max3f(float a, float b, float c) {
    return fmaxf(fmaxf(a, b), c);
}

__global__ __launch_bounds__(256, 4)
void soft_skel_v3(const float* __restrict__ img, float* __restrict__ out) {
    __shared__ __align__(16) float raw[RAW_H][RAW_S];
    __shared__ __align__(16) float ebuf[EB_H][EB_S];

    const int tid = threadIdx.x;
    const int w0 = blockIdx.x * TW;
    const int h0 = blockIdx.y * TH;
    const int n  = blockIdx.z / NCHUNK;
    const int ch = blockIdx.z - n * NCHUNK;
    const int z0 = ch * CD;

    const float* vol  = img + (size_t)n * (D_ * H_ * W_);
    float*       ovol = out + (size_t)n * (D_ * H_ * W_);

    const float PINF = INFINITY;

    // ---- D/E geometry: thread owns output row ty, cols xx..xx+7
    const int ty = tid >> 3;
    const int xx = (tid & 7) * 8;

    // ---- A-stage: own-loads (always in-bounds in h,w; coalesced)
    const int own_goff = (h0 + ty) * W_ + (w0 + xx);      // global plane offset
    const int own_lds  = (ty + 2) * RAW_S + (xx + 4);     // raw word address

    // ---- A-stage: halo cells (rows 0,1,34,35 full; rows 2..33 edge groups)
    const bool h_has = tid < NHALO;
    int h_r = 0, h_g = 0;
    if (tid < 36)      { h_r = tid / 18;              h_g = tid % 18; }
    else if (tid < 72) { h_r = 34 + (tid - 36) / 18;  h_g = (tid - 36) % 18; }
    else               { int e = tid - 72; h_r = 2 + (e >> 1); h_g = (e & 1) ? 17 : 0; }
    const int  h_gh  = h0 - 2 + h_r;
    const int  h_gw  = w0 - 4 + 4 * h_g;
    const bool h_img = h_has && (h_gh >= 0) && (h_gh < H_) && (h_gw >= 0) && (h_gw <= W_ - 4);
    const int  h_goff = h_gh * W_ + h_gw;
    const int  h_lds  = h_r * RAW_S + 4 * h_g;

    // ---- B-stage TRANSPOSED tasks: task t -> row r = t%34, strip j = t/34
    const int  r0 = tid % EB_H;
    const int  c0 = (tid / EB_H) * 8;
    const bool has1 = tid < (NBTASK - 256);               // 50 second tasks
    const int  t1 = tid + 256;
    const int  r1 = t1 % EB_H;
    const int  c1 = (t1 / EB_H) * 8;

    // ---- register z-pipelines
    float pm0[8], sp0[8], pm1[8], sp1[8];  // erode z-min state per B task
    float t2A[8], t2B[8], t2C[8];          // 2D-max planes z-1, z, z+1
    float rwA[8], rwB[8], rwC[8];          // raw centers z, z+1, z+2
    #pragma unroll
    for (int j = 0; j < 8; ++j) {
        pm0[j] = sp0[j] = pm1[j] = sp1[j] = PINF;
        t2A[j] = t2B[j] = 0.f;
        rwA[j] = rwB[j] = 0.f;
    }

    auto prefetch = [&](int zz, float4 L[3]) {
        const bool zok = (zz >= 0) && (zz < D_);
        const float* plane = vol + (size_t)zz * (H_ * W_);
        float4 pv = make_float4(PINF, PINF, PINF, PINF);
        L[0] = pv; L[1] = pv; L[2] = pv;
        if (zok) {
            L[0] = *(const float4*)(plane + own_goff);
            L[1] = *(const float4*)(plane + own_goff + 4);
            if (h_img) L[2] = *(const float4*)(plane + h_goff);
        }
    };

    // B task: 2D 3x3 min of raw -> s; e(zz-1) = min(pm, s) (masked); update pipe
    auto btask = [&](int r, int cb, float pm[8], float sp[8], bool zeok) {
        float vm[10];
        {
            const float* p0 = &raw[r][0];
            const float* p1 = &raw[r + 1][0];
            const float* p2 = &raw[r + 2][0];
            int cl = cb - 1; if (cl < 0) cl = 0;
            int cr = cb + 8; if (cr > RAW_W - 1) cr = RAW_W - 1;
            vm[0] = min3f(p0[cl], p1[cl], p2[cl]);
            vm[9] = min3f(p0[cr], p1[cr], p2[cr]);
            float4 q00 = *(const float4*)(p0 + cb);
            float4 q01 = *(const float4*)(p0 + cb + 4);
            float4 q10 = *(const float4*)(p1 + cb);
            float4 q11 = *(const float4*)(p1 + cb + 4);
            float4 q20 = *(const float4*)(p2 + cb);
            float4 q21 = *(const float4*)(p2 + cb + 4);
            vm[1] = min3f(q00.x, q10.x, q20.x);
            vm[2] = min3f(q00.y, q10.y, q20.y);
            vm[3] = min3f(q00.z, q10.z, q20.z);
            vm[4] = min3f(q00.w, q10.w, q20.w);
            vm[5] = min3f(q01.x, q11.x, q21.x);
            vm[6] = min3f(q01.y, q11.y, q21.y);
            vm[7] = min3f(q01.z, q11.z, q21.z);
            vm[8] = min3f(q01.w, q11.w, q21.w);
        }
        float s[8];
        #pragma unroll
        for (int j = 0; j < 8; ++j) s[j] = min3f(vm[j], vm[j + 1], vm[j + 2]);

        const bool rok = zeok && ((unsigned)(h0 - 1 + r) < (unsigned)H_);
        float e[8];
        #pragma unroll
        for (int j = 0; j < 8; ++j) {
            float ev = fminf(pm[j], s[j]);
            bool ok = rok && ((unsigned)(w0 - 4 + cb + j) < (unsigned)W_);
            e[j] = ok ? ev : -PINF;
            pm[j] = fminf(sp[j], s[j]);
            sp[j] = s[j];
        }
        *(float4*)&ebuf[r][cb]     = make_float4(e[0], e[1], e[2], e[3]);
        *(float4*)&ebuf[r][cb + 4] = make_float4(e[4], e[5], e[6], e[7]);
    };

    float4 L[3];
    prefetch(z0 - 2, L);
    const int zzend = z0 + CD + 1;

    for (int zz = z0 - 2; zz <= zzend; ++zz) {
        // ---- A: commit prefetched raw plane zz to LDS
        *(float4*)(&raw[0][0] + own_lds)     = L[0];
        *(float4*)(&raw[0][0] + own_lds + 4) = L[1];
        if (h_has) *(float4*)(&raw[0][0] + h_lds) = L[2];

        // capture raw centers of plane zz straight from the prefetch regs
        rwC[0] = L[0].x; rwC[1] = L[0].y; rwC[2] = L[0].z; rwC[3] = L[0].w;
        rwC[4] = L[1].x; rwC[5] = L[1].y; rwC[6] = L[1].z; rwC[7] = L[1].w;

        // start loading plane zz+1 while this one is processed
        if (zz < zzend) prefetch(zz + 1, L);
        __syncthreads();

        // ---- B: s2d(zz) + full erode e(zz-1) -> ebuf
        const int  ze   = zz - 1;
        const bool zeok = (ze >= 0) && (ze < D_);
        btask(r0, c0, pm0, sp0, zeok);
        if (has1) btask(r1, c1, pm1, sp1, zeok);
        __syncthreads();

        // ---- D: 2D 3x3 max of e(zz-1) -> t2C (registers)
        {
            float vm[10];
            const float* p0 = &ebuf[ty][0];
            const float* p1 = &ebuf[ty + 1][0];
            const float* p2 = &ebuf[ty + 2][0];
            vm[0] = max3f(p0[xx + 3], p1[xx + 3], p2[xx + 3]);
            vm[9] = max3f(p0[xx + 12], p1[xx + 12], p2[xx + 12]);
            float4 q00 = *(const float4*)(p0 + xx + 4);
            float4 q01 = *(const float4*)(p0 + xx + 8);
            float4 q10 = *(const float4*)(p1 + xx + 4);
            float4 q11 = *(const float4*)(p1 + xx + 8);
            float4 q20 = *(const float4*)(p2 + xx + 4);
            float4 q21 = *(const float4*)(p2 + xx + 8);
            vm[1] = max3f(q00.x, q10.x, q20.x);
            vm[2] = max3f(q00.y, q10.y, q20.y);
            vm[3] = max3f(q00.z, q10.z, q20.z);
            vm[4] = max3f(q00.w, q10.w, q20.w);
            vm[5] = max3f(q01.x, q11.x, q21.x);
            vm[6] = max3f(q01.y, q11.y, q21.y);
            vm[7] = max3f(q01.z, q11.z, q21.z);
            vm[8] = max3f(q01.w, q11.w, q21.w);
            #pragma unroll
            for (int j = 0; j < 8; ++j) t2C[j] = max3f(vm[j], vm[j + 1], vm[j + 2]);
        }

        // ---- E: output plane z = zz-2: relu(raw - max over t2 planes)
        if (zz >= z0 + 2) {
            const int z = zz - 2;
            float* op = ovol + ((size_t)z * H_ + (h0 + ty)) * W_ + (w0 + xx);
            float o[8];
            #pragma unroll
            for (int j = 0; j < 8; ++j) {
                float opened = max3f(t2A[j], t2B[j], t2C[j]);
                float v = rwA[j] - opened;
                o[j] = v > 0.f ? v : 0.f;
            }
            *(float4*)op       = make_float4(o[0], o[1], o[2], o[3]);
            *(float4*)(op + 4) = make_float4(o[4], o[5], o[6], o[7]);
        }

        // ---- shift register pipelines
        #pragma unroll
        for (int j = 0; j < 8; ++j) {
            t2A[j] = t2B[j]; t2B[j] = t2C[j];
            rwA[j] = rwB[j]; rwB[j] = rwC[j];
        }
    }
}

extern "C" void kernel_launch(void* const* d_in, const int* in_sizes, int n_in,
                              void* d_out, int out_size, void* d_ws, size_t ws_size,
                              hipStream_t stream) {
    const float* img = (const float*)d_in[0];
    float* out = (float*)d_out;

    dim3 grid(W_ / TW, H_ / TH, NB * NCHUNK);   // (4, 8, 32) = 1024 blocks
    dim3 block(256);
    soft_skel_v3<<<grid, block, 0, stream>>>(img, out);
}